// Round 6
// baseline (4791.474 us; speedup 1.0000x reference)
//
#include <hip/hip_runtime.h>

// DeepAR MI355X round 6: persistent kernel, layer-split WGs, LDS weights
// (32x32x16 MFMA frag layout). NEW: write-once T-indexed rings for h-state
// and mu/sigma partials => NO acquire-inv in the barrier (no L2 wipe per
// window). h published via sc1 (LLC-direct) stores; consumers use plain
// cached loads (first touch per XCD is provably fresh, then L2-shared).
// Falls back to ring-2 + per-barrier inv if ws_size is too small.
// B=128, T=160, F=512, E=64, H=1024, L=2. Output [B,T,2] fp32.

#define B_   128
#define T_   160
#define FD   512
#define E_   64
#define H_   1024
#define NT   512
#define NBLK 256
#define CH0  100                     // L0 K-chunks (32 feat, 4 lab, 64 h0)
#define CH1  128                     // L1 K-chunks (64 h0cur, 64 h1prev)
#define HT_ELEMS (64 * 4 * 512)      // per-slot h tile elems (= B_*H_)

typedef unsigned short u16;
typedef __attribute__((ext_vector_type(8))) short bf16x8;
typedef __attribute__((ext_vector_type(16))) float f32x16;

__device__ __forceinline__ bf16x8 ld8(const u16* p) {
    return *reinterpret_cast<const bf16x8*>(p);
}
__device__ __forceinline__ f32x16 mfma32(bf16x8 a, bf16x8 b, f32x16 c) {
    return __builtin_amdgcn_mfma_f32_32x32x16_bf16(a, b, c, 0, 0, 0);
}
__device__ __forceinline__ u16 f2bf(float x) {
    unsigned u = __float_as_uint(x);
    u += 0x7FFFu + ((u >> 16) & 1u);   // RNE
    return (u16)(u >> 16);
}
__device__ __forceinline__ float sigm(float x)  { return 1.f / (1.f + __expf(-x)); }
__device__ __forceinline__ float tanh_(float x) { return 1.f - 2.f / (__expf(2.f * x) + 1.f); }
__device__ __forceinline__ float softp(float x) { return x > 20.f ? x : log1pf(__expf(x)); }

__device__ __forceinline__ void st_u32(unsigned* p, unsigned v) {
    __hip_atomic_store(p, v, __ATOMIC_RELAXED, __HIP_MEMORY_SCOPE_AGENT);
}
__device__ __forceinline__ void st_f32(float* p, float v) {
    __hip_atomic_store(p, v, __ATOMIC_RELAXED, __HIP_MEMORY_SCOPE_AGENT);
}

// Grid barrier: 8 spread arrival lines; WG0 aggregates -> release flag.
// Relaxed LLC polls; acquire-inv only when doInv (small-ring fallback).
__device__ __forceinline__ void gbar(unsigned* actr, unsigned* rel, int blk,
                                     unsigned phase, bool doInv) {
    __syncthreads();   // drains vmcnt: all sc1 stores / atomics complete at LLC
    if (threadIdx.x == 0) {
        __hip_atomic_fetch_add(&actr[(blk & 7) * 32], 1u,
                               __ATOMIC_RELAXED, __HIP_MEMORY_SCOPE_AGENT);
        if (blk == 0) {
            for (;;) {
                unsigned s = 0;
                #pragma unroll
                for (int i = 0; i < 8; ++i)
                    s += __hip_atomic_load(&actr[i * 32], __ATOMIC_RELAXED,
                                           __HIP_MEMORY_SCOPE_AGENT);
                if (s >= (unsigned)NBLK * phase) break;
                __builtin_amdgcn_s_sleep(2);
            }
            __hip_atomic_store(rel, phase, __ATOMIC_RELAXED, __HIP_MEMORY_SCOPE_AGENT);
        } else {
            while (__hip_atomic_load(rel, __ATOMIC_RELAXED, __HIP_MEMORY_SCOPE_AGENT) < phase)
                __builtin_amdgcn_s_sleep(2);
        }
        if (doInv)
            (void)__hip_atomic_load(rel, __ATOMIC_ACQUIRE, __HIP_MEMORY_SCOPE_AGENT);
    }
    __atomic_signal_fence(__ATOMIC_ACQUIRE);   // compiler-only ordering
    __syncthreads();
}

// ---------------- prologue kernels ----------------

__global__ void detect_mask(const unsigned* __restrict__ m, int* __restrict__ flags) {
    int i = blockIdx.x * 256 + threadIdx.x;   // exactly 5120 words (20480 bytes)
    unsigned w = m[i];
    if (w > 1u) atomicOr(&flags[0], 1);
    if (w != 0u && w != 0x3F800000u) atomicOr(&flags[1], 1);
}

// feat [B][T][512] fp32 -> fb2 [T][c=32][mblk=4][512] bf16 (MFMA A-frag tiles)
__global__ void featconv(const float* __restrict__ feat, u16* __restrict__ fb2) {
    int i = blockIdx.x * 256 + threadIdx.x;   // [0, 160*16384) float4 units
    int t = i >> 14;
    int u = i & 16383;
    int c = u >> 9;
    int r = u & 511;
    int mm = r >> 7;
    int l  = (r >> 1) & 63;
    int jj = r & 1;
    int b = mm * 32 + (l & 31);
    int k = c * 16 + (l >> 5) * 8 + jj * 4;
    float4 v = reinterpret_cast<const float4*>(feat)[((size_t)b * T_ + t) * 128 + (k >> 2)];
    ushort4 o = make_ushort4(f2bf(v.x), f2bf(v.y), f2bf(v.z), f2bf(v.w));
    reinterpret_cast<ushort4*>(fb2)[((((size_t)t * 32 + c) * 4 + mm) * 512 + l * 8 + jj * 4) >> 2] = o;
}

// ---------------- persistent kernel ----------------

struct SM0 {                       // layer-0 WGs
    u16   bw[CH0 * 512];           // 102400 B, B-frags: bw[ch*512 + lane*8 + j]
    u16   labf[4 * 4 * 512];       // label A-frag tiles
    float gtb[4224];               // K-reduce scratch [16][256] / gates [128][33]
    float mu_s[128];
    float uu[32], vv[32], bias[32];
    float mwv[8], swv[8];
    unsigned char msk[128];
};
struct SM1 {                       // layer-1 WGs
    u16   bw[CH1 * 512];           // 131072 B
    float gtb[4224];
    float bias[32];
    float mwv[8], swv[8];
};
union SMU { SM0 a; SM1 b; };

__global__ void __launch_bounds__(NT, 2) persist(
    const u16* __restrict__ fb2, const float* __restrict__ emb,
    const void* __restrict__ mask, const int* __restrict__ flags,
    const float* __restrict__ Wih0, const float* __restrict__ Whh0,
    const float* __restrict__ bih0, const float* __restrict__ bhh0,
    const float* __restrict__ Wih1, const float* __restrict__ Whh1,
    const float* __restrict__ bih1, const float* __restrict__ bhh1,
    const float* __restrict__ Wtgt, const float* __restrict__ btgt,
    const float* __restrict__ muw, const float* __restrict__ mubp,
    const float* __restrict__ sgw, const float* __restrict__ sgbp,
    u16* __restrict__ h0T, u16* __restrict__ h1T,
    float* __restrict__ muacc, float* __restrict__ sgacc,
    unsigned* __restrict__ actr, unsigned* __restrict__ relf,
    float* __restrict__ out, int bigRing)
{
    __shared__ SMU smu;
    const int tid  = threadIdx.x;
    const int blk  = blockIdx.x;
    const bool isL0 = blk < 128;
    const int g    = isL0 ? blk : blk - 128;   // hidden units g*8..g*8+7
    const int wv   = tid >> 6;
    const int m    = wv & 3;                   // M-tile (rows m*32..m*32+31)
    const int s    = wv >> 2;                  // K-split half
    const int lane = tid & 63;
    const int l31  = lane & 31;
    const bool doInv = !bigRing;

    const float mub_r = mubp[0], sgb_r = sgbp[0];

    // ---- one-time init: pack weights into MFMA B-frag layout in LDS ----
    if (isL0) {
        SM0& s0 = smu.a;
        for (int i = tid; i < CH0 * 512; i += NT) {
            int ch = i >> 9, r = i & 511, l = r >> 3, jj = r & 7;
            int pc = l & 31;
            int kk = ch * 16 + (l >> 5) * 8 + jj;
            int q = pc & 3, j = pc >> 2;
            int row = q * H_ + g * 8 + j;
            float v = (kk < 576) ? Wih0[row * 576 + kk]
                                 : Whh0[(size_t)row * H_ + (kk - 576)];
            s0.bw[i] = f2bf(v);
        }
        if (tid < 32) {
            int pc = tid, q = pc & 3, j = pc >> 2;
            int row = q * H_ + g * 8 + j;
            s0.bias[pc] = bih0[row] + bhh0[row];
            float su = 0.f, sv = 0.f;
            for (int e = 0; e < 64; ++e) {       // rank-1 label vectors
                float wl = Wih0[row * 576 + 512 + e];
                su += Wtgt[e] * wl;
                sv += btgt[e] * wl;
            }
            s0.uu[pc] = su; s0.vv[pc] = sv;
        }
        if (tid < 8) {
            int h = g * 8 + tid;
            s0.mwv[tid] = muw[2 * h]; s0.swv[tid] = sgw[2 * h];
        }
    } else {
        SM1& s1 = smu.b;
        for (int i = tid; i < CH1 * 512; i += NT) {
            int ch = i >> 9, r = i & 511, l = r >> 3, jj = r & 7;
            int pc = l & 31;
            int kk = ch * 16 + (l >> 5) * 8 + jj;
            int q = pc & 3, j = pc >> 2;
            int row = q * H_ + g * 8 + j;
            float v = (kk < 1024) ? Wih1[(size_t)row * H_ + kk]
                                  : Whh1[(size_t)row * H_ + (kk - 1024)];
            s1.bw[i] = f2bf(v);
        }
        if (tid < 32) {
            int pc = tid, q = pc & 3, j = pc >> 2;
            int row = q * H_ + g * 8 + j;
            s1.bias[pc] = bih1[row] + bhh1[row];
        }
        if (tid < 8) {
            int h = g * 8 + tid;
            s1.mwv[tid] = muw[2 * h + 1]; s1.swv[tid] = sgw[2 * h + 1];
        }
    }
    const int nonbin = flags[0], nonfl = flags[1];
    __syncthreads();

    float creg0 = 0.f, creg1 = 0.f;
    f32x16 acc;
    #pragma unroll
    for (int r = 0; r < 16; ++r) acc[r] = 0.f;

    // label tile builder (A-frag layout; mask-zeroed rows when use_mask)
    auto build_lab = [&](int t1, bool use_mask) {
        SM0& s0 = smu.a;
        for (int i = tid; i < 8192; i += NT) {
            int e = i & 63, b = i >> 6;
            bool um = false;
            if (use_mask) {
                int mi = b * T_ + t1;
                um = !nonbin ? (reinterpret_cast<const int*>(mask)[mi] != 0)
                   : !nonfl  ? (reinterpret_cast<const float*>(mask)[mi] != 0.f)
                             : (reinterpret_cast<const unsigned char*>(mask)[mi] != 0);
            }
            float v = um ? 0.f : emb[((size_t)b * T_ + t1) * E_ + e];
            int c = e >> 4, kk = e & 15, hk = kk >> 3, j = kk & 7;
            int l = hk * 32 + (b & 31), mb = b >> 5;
            s0.labf[(c * 4 + mb) * 512 + l * 8 + j] = f2bf(v);
        }
    };

    // pre-loop: feat(0)+lab(0) GEMM
    if (isL0) {
        build_lab(0, false);
        __syncthreads();
        SM0& s0 = smu.a;
        #pragma unroll 6
        for (int c = 0; c < 18; ++c) {
            int ch = s * 18 + c;
            bf16x8 a;
            if (ch < 32) a = ld8(fb2 + (((size_t)0 * 32 + ch) * 4 + m) * 512 + lane * 8);
            else         a = *(const bf16x8*)&s0.labf[((ch - 32) * 4 + m) * 512 + lane * 8];
            bf16x8 b = *(const bf16x8*)&s0.bw[ch * 512 + lane * 8];
            acc = mfma32(a, b, acc);
        }
    }

    unsigned bc = 0;
    for (int t = 0; t < T_; ++t) {
        const int slotC = bigRing ? t : (t & 1);
        const int slotP = bigRing ? (t - 1) : ((t - 1) & 1);   // only used when t>0

        // ===================== window 1 =====================
        if (isL0) {
            SM0& s0 = smu.a;
            if (t > 0) {
                if (tid < 128) {     // mu(t-1) + mask(t), latency hidden by GEMM
                    const float4* pa = (const float4*)&muacc[((size_t)(t - 1) * 128 + tid) * 16];
                    float4 x = pa[0], y = pa[1], z = pa[2], w4 = pa[3];
                    s0.mu_s[tid] = (x.x + x.y) + (x.z + x.w) + (y.x + y.y) + (y.z + y.w)
                                 + (z.x + z.y) + (z.z + z.w) + (w4.x + w4.y) + (w4.z + w4.w)
                                 + mub_r;
                    int mi = tid * T_ + t;
                    bool um = !nonbin ? (reinterpret_cast<const int*>(mask)[mi] != 0)
                            : !nonfl  ? (reinterpret_cast<const float*>(mask)[mi] != 0.f)
                                      : (reinterpret_cast<const unsigned char*>(mask)[mi] != 0);
                    s0.msk[tid] = um ? 1 : 0;
                }
                const u16* hp = h0T + (size_t)slotP * HT_ELEMS;
                #pragma unroll 16
                for (int c = 0; c < 32; ++c) {
                    int ch = s * 32 + c;
                    bf16x8 a = ld8(hp + ((size_t)ch * 4 + m) * 512 + lane * 8);
                    bf16x8 b = *(const bf16x8*)&s0.bw[(36 + ch) * 512 + lane * 8];
                    acc = mfma32(a, b, acc);
                }
            }
            // K-split reduce -> gates
            if (s == 1) {
                #pragma unroll
                for (int r = 0; r < 16; ++r) s0.gtb[r * 256 + m * 64 + lane] = acc[r];
            }
            __syncthreads();
            if (t > 0 && tid == 0) {
                const float4* ps = (const float4*)&sgacc[((size_t)(t - 1) * 128 + g) * 16];
                float4 x = ps[0], y = ps[1], z = ps[2], w4 = ps[3];
                float sg = (x.x + x.y) + (x.z + x.w) + (y.x + y.y) + (y.z + y.w)
                         + (z.x + z.y) + (z.z + z.w) + (w4.x + w4.y) + (w4.z + w4.w)
                         + sgb_r;
                st_f32(&out[((size_t)g * T_ + (t - 1)) * 2 + 0], s0.mu_s[g]);
                st_f32(&out[((size_t)g * T_ + (t - 1)) * 2 + 1], softp(sg));
            }
            f32x16 tot;
            if (s == 0) {
                #pragma unroll
                for (int r = 0; r < 16; ++r) tot[r] = acc[r] + s0.gtb[r * 256 + m * 64 + lane];
            }
            __syncthreads();
            if (s == 0) {
                #pragma unroll
                for (int r = 0; r < 16; ++r) {
                    int row = m * 32 + (r & 3) + 8 * (r >> 2) + 4 * (lane >> 5);
                    s0.gtb[row * 33 + l31] = tot[r];
                }
            }
            __syncthreads();
            // cell0 + h0 publish (fragment-tiled, sc1 full-line) + partial atomics
            u16* hw = h0T + (size_t)slotC * HT_ELEMS;
            const int c_ = g >> 1, half = g & 1;
            #pragma unroll
            for (int p = 0; p < 2; ++p) {
                int id = tid + p * NT;
                int b = id >> 3, j = id & 7;
                float gi = s0.gtb[b * 33 + 4 * j + 0] + s0.bias[4 * j + 0];
                float gf = s0.gtb[b * 33 + 4 * j + 1] + s0.bias[4 * j + 1];
                float gg = s0.gtb[b * 33 + 4 * j + 2] + s0.bias[4 * j + 2];
                float go = s0.gtb[b * 33 + 4 * j + 3] + s0.bias[4 * j + 3];
                if (t > 0 && s0.msk[b]) {       // rank-1 mu-label term (fp32 exact)
                    float mu = s0.mu_s[b];
                    gi += mu * s0.uu[4 * j + 0] + s0.vv[4 * j + 0];
                    gf += mu * s0.uu[4 * j + 1] + s0.vv[4 * j + 1];
                    gg += mu * s0.uu[4 * j + 2] + s0.vv[4 * j + 2];
                    go += mu * s0.uu[4 * j + 3] + s0.vv[4 * j + 3];
                }
                float cold = (p == 0) ? creg0 : creg1;
                float cn = sigm(gf) * cold + sigm(gi) * tanh_(gg);
                float hn = sigm(go) * tanh_(cn);
                if (p == 0) creg0 = cn; else creg1 = cn;
                unsigned hv = f2bf(hn);
                unsigned other = (unsigned)__shfl_xor((int)hv, 1);
                if ((j & 1) == 0) {
                    int l = half * 32 + (b & 31), mb = b >> 5;
                    st_u32(reinterpret_cast<unsigned*>(hw + ((size_t)(c_ * 4 + mb) * 512 + l * 8 + j)),
                           hv | (other << 16));
                }
                float pmu = hn * s0.mwv[j], psg = hn * s0.swv[j];
                pmu += __shfl_xor(pmu, 1); pmu += __shfl_xor(pmu, 2); pmu += __shfl_xor(pmu, 4);
                psg += __shfl_xor(psg, 1); psg += __shfl_xor(psg, 2); psg += __shfl_xor(psg, 4);
                if (j == 0) {
                    atomicAdd(&muacc[((size_t)t * 128 + b) * 16 + (g & 15)], pmu);
                    atomicAdd(&sgacc[((size_t)t * 128 + b) * 16 + (g & 15)], psg);
                }
            }
            #pragma unroll
            for (int r = 0; r < 16; ++r) acc[r] = 0.f;
        } else {
            SM1& s1 = smu.b;
            if (t > 0) {   // h1prev GEMM (chunks 64..127)
                const u16* hp = h1T + (size_t)slotP * HT_ELEMS;
                #pragma unroll 16
                for (int c = 0; c < 32; ++c) {
                    int ch = s * 32 + c;
                    bf16x8 a = ld8(hp + ((size_t)ch * 4 + m) * 512 + lane * 8);
                    bf16x8 b = *(const bf16x8*)&s1.bw[(64 + ch) * 512 + lane * 8];
                    acc = mfma32(a, b, acc);
                }
            }
        }
        gbar(actr, relf, blk, ++bc, doInv);   // h0(t) + L0 partials at LLC

        // ===================== window 2 =====================
        if (isL0) {
            SM0& s0 = smu.a;
            if (t + 1 < T_) {          // pre-GEMM feat(t+1) + mask-zeroed emb(t+1)
                build_lab(t + 1, true);
                __syncthreads();
                #pragma unroll 6
                for (int c = 0; c < 18; ++c) {
                    int ch = s * 18 + c;
                    bf16x8 a;
                    if (ch < 32) a = ld8(fb2 + (((size_t)(t + 1) * 32 + ch) * 4 + m) * 512 + lane * 8);
                    else         a = *(const bf16x8*)&s0.labf[((ch - 32) * 4 + m) * 512 + lane * 8];
                    bf16x8 b = *(const bf16x8*)&s0.bw[ch * 512 + lane * 8];
                    acc = mfma32(a, b, acc);
                }
            }
        } else {
            SM1& s1 = smu.b;
            {   // h0cur GEMM (chunks 0..63)
                const u16* hp = h0T + (size_t)slotC * HT_ELEMS;
                #pragma unroll 16
                for (int c = 0; c < 32; ++c) {
                    int ch = s * 32 + c;
                    bf16x8 a = ld8(hp + ((size_t)ch * 4 + m) * 512 + lane * 8);
                    bf16x8 b = *(const bf16x8*)&s1.bw[ch * 512 + lane * 8];
                    acc = mfma32(a, b, acc);
                }
            }
            if (s == 1) {
                #pragma unroll
                for (int r = 0; r < 16; ++r) s1.gtb[r * 256 + m * 64 + lane] = acc[r];
            }
            __syncthreads();
            f32x16 tot;
            if (s == 0) {
                #pragma unroll
                for (int r = 0; r < 16; ++r) tot[r] = acc[r] + s1.gtb[r * 256 + m * 64 + lane];
            }
            __syncthreads();
            if (s == 0) {
                #pragma unroll
                for (int r = 0; r < 16; ++r) {
                    int row = m * 32 + (r & 3) + 8 * (r >> 2) + 4 * (lane >> 5);
                    s1.gtb[row * 33 + l31] = tot[r];
                }
            }
            __syncthreads();
            // cell1 + h1 publish + partial atomics
            u16* hw = h1T + (size_t)slotC * HT_ELEMS;
            const int c_ = g >> 1, half = g & 1;
            #pragma unroll
            for (int p = 0; p < 2; ++p) {
                int id = tid + p * NT;
                int b = id >> 3, j = id & 7;
                float gi = s1.gtb[b * 33 + 4 * j + 0] + s1.bias[4 * j + 0];
                float gf = s1.gtb[b * 33 + 4 * j + 1] + s1.bias[4 * j + 1];
                float gg = s1.gtb[b * 33 + 4 * j + 2] + s1.bias[4 * j + 2];
                float go = s1.gtb[b * 33 + 4 * j + 3] + s1.bias[4 * j + 3];
                float cold = (p == 0) ? creg0 : creg1;
                float cn = sigm(gf) * cold + sigm(gi) * tanh_(gg);
                float hn = sigm(go) * tanh_(cn);
                if (p == 0) creg0 = cn; else creg1 = cn;
                unsigned hv = f2bf(hn);
                unsigned other = (unsigned)__shfl_xor((int)hv, 1);
                if ((j & 1) == 0) {
                    int l = half * 32 + (b & 31), mb = b >> 5;
                    st_u32(reinterpret_cast<unsigned*>(hw + ((size_t)(c_ * 4 + mb) * 512 + l * 8 + j)),
                           hv | (other << 16));
                }
                float pmu = hn * s1.mwv[j], psg = hn * s1.swv[j];
                pmu += __shfl_xor(pmu, 1); pmu += __shfl_xor(pmu, 2); pmu += __shfl_xor(pmu, 4);
                psg += __shfl_xor(psg, 1); psg += __shfl_xor(psg, 2); psg += __shfl_xor(psg, 4);
                if (j == 0) {
                    atomicAdd(&muacc[((size_t)t * 128 + b) * 16 + (g & 15)], pmu);
                    atomicAdd(&sgacc[((size_t)t * 128 + b) * 16 + (g & 15)], psg);
                }
            }
            #pragma unroll
            for (int r = 0; r < 16; ++r) acc[r] = 0.f;
        }
        gbar(actr, relf, blk, ++bc, doInv);   // h1(t) + all partials at LLC
    }

    // ---- final output t = T_-1 ----
    if (isL0 && tid == 0) {
        const float4* pm = (const float4*)&muacc[((size_t)(T_ - 1) * 128 + g) * 16];
        float4 x = pm[0], y = pm[1], z = pm[2], w4 = pm[3];
        float mu = (x.x + x.y) + (x.z + x.w) + (y.x + y.y) + (y.z + y.w)
                 + (z.x + z.y) + (z.z + z.w) + (w4.x + w4.y) + (w4.z + w4.w) + mub_r;
        const float4* ps = (const float4*)&sgacc[((size_t)(T_ - 1) * 128 + g) * 16];
        float4 a = ps[0], b = ps[1], c = ps[2], d = ps[3];
        float sg = (a.x + a.y) + (a.z + a.w) + (b.x + b.y) + (b.z + b.w)
                 + (c.x + c.y) + (c.z + c.w) + (d.x + d.y) + (d.z + d.w) + sgb_r;
        st_f32(&out[((size_t)g * T_ + (T_ - 1)) * 2 + 0], mu);
        st_f32(&out[((size_t)g * T_ + (T_ - 1)) * 2 + 1], softp(sg));
    }
}

// ---------------- host ----------------

extern "C" void kernel_launch(void* const* d_in, const int* in_sizes, int n_in,
                              void* d_out, int out_size, void* d_ws, size_t ws_size,
                              hipStream_t stream) {
    const float* feat = (const float*)d_in[0];
    const float* emb  = (const float*)d_in[1];
    const void*  mask = d_in[2];
    const float* Wih0 = (const float*)d_in[3];
    const float* Whh0 = (const float*)d_in[4];
    const float* bih0 = (const float*)d_in[5];
    const float* bhh0 = (const float*)d_in[6];
    const float* Wih1 = (const float*)d_in[7];
    const float* Whh1 = (const float*)d_in[8];
    const float* bih1 = (const float*)d_in[9];
    const float* bhh1 = (const float*)d_in[10];
    const float* Wtgt = (const float*)d_in[11];
    const float* btgt = (const float*)d_in[12];
    const float* muw  = (const float*)d_in[13];
    const float* mub  = (const float*)d_in[14];
    const float* sgw  = (const float*)d_in[15];
    const float* sgb  = (const float*)d_in[16];
    float* out = (float*)d_out;
    char* ws = (char*)d_ws;
    (void)in_sizes; (void)n_in; (void)out_size;

    size_t off = 0;
    auto alloc = [&](size_t bytes) {
        size_t o = off;
        off = (off + bytes + 255) & ~(size_t)255;
        return o;
    };
    size_t o_flags = alloc(256);
    size_t o_actr  = alloc(8 * 32 * 4);
    size_t o_rel   = alloc(256);
    size_t o_muacc = alloc((size_t)T_ * 128 * 16 * 4);   // T-indexed, write-once
    size_t o_sgacc = alloc((size_t)T_ * 128 * 16 * 4);
    size_t zero_end = off;

    size_t fb2b       = (size_t)T_ * 32 * 4 * 512 * 2;
    size_t hbytes_big = (size_t)T_ * HT_ELEMS * 2;
    int bigRing = (off + 2 * (hbytes_big + 256) + fb2b + 512 <= ws_size) ? 1 : 0;
    size_t hbytes = bigRing ? hbytes_big : (size_t)2 * HT_ELEMS * 2;

    size_t o_h0  = alloc(hbytes);
    size_t o_h1  = alloc(hbytes);
    size_t o_fb2 = alloc(fb2b);

    int*      flags = (int*)(ws + o_flags);
    unsigned* actr  = (unsigned*)(ws + o_actr);
    unsigned* relf  = (unsigned*)(ws + o_rel);
    float*    muacc = (float*)(ws + o_muacc);
    float*    sgacc = (float*)(ws + o_sgacc);
    u16*      h0    = (u16*)(ws + o_h0);
    u16*      h1    = (u16*)(ws + o_h1);
    u16*      fb2   = (u16*)(ws + o_fb2);

    hipMemsetAsync(ws, 0, zero_end, stream);
    detect_mask<<<20, 256, 0, stream>>>((const unsigned*)mask, flags);
    featconv<<<10240, 256, 0, stream>>>(feat, fb2);

    persist<<<NBLK, NT, 0, stream>>>(
        fb2, emb, mask, flags,
        Wih0, Whh0, bih0, bhh0,
        Wih1, Whh1, bih1, bhh1,
        Wtgt, btgt, muw, mub, sgw, sgb,
        h0, h1, muacc, sgacc, actr, relf, out, bigRing);
}